// Round 15
// baseline (353.274 us; speedup 1.0000x reference)
//
#include <hip/hip_runtime.h>
#include <cstdint>
#include <cstddef>

typedef float f32x4 __attribute__((ext_vector_type(4)));
typedef float f32x16 __attribute__((ext_vector_type(16)));
typedef __bf16 bf16x8 __attribute__((ext_vector_type(8)));
typedef __bf16 bf16x4 __attribute__((ext_vector_type(4)));
typedef uint32_t u32x4 __attribute__((ext_vector_type(4)));

static constexpr int BSZ = 2, SL = 2048, DM = 1024, NH = 16, HD = 64;
static constexpr int MROWS = BSZ * SL;                 // 4096
static constexpr float LOG2E = 1.4426950408889634f;
static constexpr float QSCALE = 0.03125f * LOG2E;      // D^-0.5 * log2(e)

__device__ __forceinline__ f32x4 mfma16(bf16x8 a, bf16x8 b, f32x4 c) {
    return __builtin_amdgcn_mfma_f32_16x16x32_bf16(a, b, c, 0, 0, 0);
}
__device__ __forceinline__ f32x16 mfma32(bf16x8 a, bf16x8 b, f32x16 c) {
    return __builtin_amdgcn_mfma_f32_32x32x16_bf16(a, b, c, 0, 0, 0);
}
__device__ __forceinline__ uint32_t pkbf(float lo, float hi) {
    uint16_t a = __builtin_bit_cast(uint16_t, (__bf16)lo);
    uint16_t b = __builtin_bit_cast(uint16_t, (__bf16)hi);
    return ((uint32_t)b << 16) | (uint32_t)a;
}
// raw v_exp_f32 (2^x); inputs bounded, no denormal guard needed (r10-proven)
__device__ __forceinline__ float fexp2(float x) {
#if __has_builtin(__builtin_amdgcn_exp2f)
    return __builtin_amdgcn_exp2f(x);
#else
    float r; asm volatile("v_exp_f32 %0, %1" : "=v"(r) : "v"(x)); return r;
#endif
}
// async global->LDS, 16B per lane; lds dest = wave-uniform base + lane*16
__device__ __forceinline__ void gload16(const void* g, void* l) {
    __builtin_amdgcn_global_load_lds(
        (const __attribute__((address_space(1))) uint32_t*)g,
        (__attribute__((address_space(3))) uint32_t*)l, 16, 0, 0);
}

// ---------- cast f32 -> bf16, vectorized x4 ----------
__global__ __launch_bounds__(256) void r15_cast(const float* __restrict__ in,
                                                __bf16* __restrict__ out, int n) {
    int i = (blockIdx.x * 256 + threadIdx.x) * 4;
    if (i >= n) return;
    float4 v = *(const float4*)&in[i];
    bf16x4 o;
    o.x = (__bf16)v.x; o.y = (__bf16)v.y; o.z = (__bf16)v.z; o.w = (__bf16)v.w;
    *(bf16x4*)&out[i] = o;
}

// ---------- transpose [R][C] f32 -> [C][R] bf16 ----------
__global__ __launch_bounds__(256) void r15_transpose_cast(const float* __restrict__ in,
                                                          __bf16* __restrict__ out,
                                                          int R, int C) {
    __shared__ float tile[32][33];
    int c0 = blockIdx.x * 32, r0 = blockIdx.y * 32;
    int tx = threadIdx.x & 31, ty = threadIdx.x >> 5;   // 256 threads: ty 0..7
#pragma unroll
    for (int i = 0; i < 32; i += 8)
        tile[ty + i][tx] = in[(size_t)(r0 + ty + i) * C + c0 + tx];
    __syncthreads();
#pragma unroll
    for (int i = 0; i < 32; i += 8)
        out[(size_t)(c0 + ty + i) * R + r0 + tx] = (__bf16)tile[tx][ty + i];
}

// ---------- GEMM (r10-proven, BK=32, global_load_lds): C = A * Bt^T ----------
// EPI==1: scatter into Q (scaled), K, V^T.  EPI==0: f32 row-major out.
template <int EPI, int BN>
__global__ __launch_bounds__(256) void r15_gemm(
    const __bf16* __restrict__ A, const __bf16* __restrict__ Bt,
    float* __restrict__ ob, int M, int N, int K,
    __bf16* __restrict__ qb, __bf16* __restrict__ kb, __bf16* __restrict__ vtb)
{
    constexpr int BM = 128, BK = 32;
    constexpr int FN = BN / 32;               // acc cols per wave (128->4, 64->2)
    __shared__ __bf16 As[BM * BK];
    __shared__ __bf16 Bs[BN * BK];
    const int tid  = threadIdx.x;
    const int m0   = blockIdx.y * BM, n0 = blockIdx.x * BN;
    const int wave = tid >> 6, lane = tid & 63;
    const int lcol = lane & 15, lgrp = lane >> 4;
    const int wm   = (wave >> 1) * 64, wn = (wave & 1) * (BN / 2);
    const int grow = lane >> 2, gcol = (lane & 3) * 8;   // staging: 16 rows/chunk

    f32x4 acc[4][FN] = {};

    for (int k0 = 0; k0 < K; k0 += BK) {
        {
            const int cA0 = 2 * wave;
            gload16(&A[(size_t)(m0 + cA0 * 16 + grow) * K + k0 + gcol], &As[cA0 * 512]);
            gload16(&A[(size_t)(m0 + (cA0 + 1) * 16 + grow) * K + k0 + gcol], &As[(cA0 + 1) * 512]);
            if constexpr (BN == 128) {
                gload16(&Bt[(size_t)(n0 + cA0 * 16 + grow) * K + k0 + gcol], &Bs[cA0 * 512]);
                gload16(&Bt[(size_t)(n0 + (cA0 + 1) * 16 + grow) * K + k0 + gcol], &Bs[(cA0 + 1) * 512]);
            } else {
                gload16(&Bt[(size_t)(n0 + wave * 16 + grow) * K + k0 + gcol], &Bs[wave * 512]);
            }
        }
        __syncthreads();
        bf16x8 af[4], bfr[FN];
#pragma unroll
        for (int f = 0; f < 4; ++f)
            af[f] = *(const bf16x8*)&As[(wm + f * 16 + lcol) * BK + lgrp * 8];
#pragma unroll
        for (int f = 0; f < FN; ++f)
            bfr[f] = *(const bf16x8*)&Bs[(wn + f * 16 + lcol) * BK + lgrp * 8];
#pragma unroll
        for (int fm = 0; fm < 4; ++fm)
#pragma unroll
            for (int fn = 0; fn < FN; ++fn)
                acc[fm][fn] = mfma16(af[fm], bfr[fn], acc[fm][fn]);
        __syncthreads();
    }

#pragma unroll
    for (int fm = 0; fm < 4; ++fm) {
#pragma unroll
        for (int fn = 0; fn < FN; ++fn) {
            int n = n0 + wn + fn * 16 + lcol;
#pragma unroll
            for (int r = 0; r < 4; ++r) {
                int m = m0 + wm + fm * 16 + lgrp * 4 + r;
                float v = acc[fm][fn][r];
                if (EPI == 0) {
                    ob[(size_t)m * N + n] = v;               // f32 output
                } else {
                    int sec = n >> 10, nm = n & 1023;
                    int h = nm >> 6, d = nm & 63;
                    int b = m >> 11, s = m & 2047;
                    size_t bh = (size_t)(b * NH + h);
                    if (sec == 0)      qb[(bh * SL + s) * HD + d]  = (__bf16)(v * QSCALE);
                    else if (sec == 1) kb[(bh * SL + s) * HD + d]  = (__bf16)v;
                    else               vtb[(bh * HD + d) * SL + s] = (__bf16)v;
                }
            }
        }
    }
}

// ---------- flash attention: BARRIER-FREE async waves ------------------------
// grid 2048 blocks (XCD-swizzled), 4 waves; block = 32 q-rows; wave w owns KV
// rows [w*512,(w+1)*512) with a PRIVATE 16KB LDS region -> zero barriers in the
// loop. Max-free softmax makes per-wave partials directly summable (1 barrier).
__global__ __launch_bounds__(256, 2) void r15_attn(
    const __bf16* __restrict__ qb, const __bf16* __restrict__ kb,
    const __bf16* __restrict__ vtb, __bf16* __restrict__ ctx)
{
    __shared__ __bf16 arena[32768];      // 64KB: wave w -> [w*8192, w*8192+8192)
    __shared__ float l_lds[4][32];
    const int L = blockIdx.x;                        // [0,2048)
    const int xcd = L & 7, j = L >> 3;               // 4 heads per XCD (2MB < L2)
    const int bh = xcd * 4 + (j & 3);
    const int qblk = j >> 2;                         // [0,64)
    const int tid  = threadIdx.x;
    const int wave = tid >> 6, lane = tid & 63;
    const int lq = lane & 31, h = lane >> 5;
    const int swz8 = lq & 7;
    const int q0 = qblk * 32;

    const __bf16* Q = qb + ((size_t)bh * SL + q0) * HD;

    // per-wave staging geometry: lane -> (row-in-8, col8); 8 chunks per matrix
    const int rl = lane >> 3, cl = lane & 7;
    const int s0off = rl * 64 + ((cl ^ rl) * 8);     // swizzled, chunk-invariant
    __bf16* Kb = &arena[wave * 8192];
    __bf16* Vb = Kb + 4096;
    const __bf16* KgL = kb  + (size_t)bh * SL * HD + (size_t)(wave * 512 + rl) * HD + cl * 8;
    const __bf16* VgL = vtb + (size_t)bh * HD * SL + (size_t)rl * SL + wave * 512 + cl * 8;

    bf16x8 qf[4];
#pragma unroll
    for (int t = 0; t < 4; ++t)
        qf[t] = *(const bf16x8*)&Q[(size_t)lq * HD + t * 16 + h * 8];

    f32x16 accT0 = {}, accT1 = {};
    float l_run = 0.f;

    int4 kpre[8], vpre[8];                           // tile-0 prefetch
#pragma unroll
    for (int c = 0; c < 8; ++c) {
        kpre[c] = *(const int4*)(KgL + c * 512);
        vpre[c] = *(const int4*)(VgL + (size_t)c * 8 * SL);
    }

    for (int t = 0; t < 8; ++t) {
        // write staged regs -> private LDS (in-order LDS pipe: safe vs own reads)
#pragma unroll
        for (int c = 0; c < 8; ++c) {
            *(int4*)(Kb + c * 512 + s0off) = kpre[c];
            *(int4*)(Vb + c * 512 + s0off) = vpre[c];
        }
        if (t + 1 < 8) {                             // prefetch next tile
#pragma unroll
            for (int c = 0; c < 8; ++c) {
                kpre[c] = *(const int4*)(KgL + (t + 1) * 4096 + c * 512);
                vpre[c] = *(const int4*)(VgL + (size_t)c * 8 * SL + (t + 1) * 64);
            }
        }
        // compute (compiler inserts wave-local lgkmcnt before first LDS read)
        f32x16 s0 = {}, s1 = {};
        __builtin_amdgcn_s_setprio(1);
#pragma unroll
        for (int t4 = 0; t4 < 4; ++t4) {
            const int cv = ((t4 * 2 + h) ^ swz8) * 8;
            bf16x8 kf0 = *(const bf16x8*)&Kb[lq * 64 + cv];
            bf16x8 kf1 = *(const bf16x8*)&Kb[(lq + 32) * 64 + cv];
            s0 = mfma32(kf0, qf[t4], s0);
            s1 = mfma32(kf1, qf[t4], s1);
        }
        __builtin_amdgcn_s_setprio(0);
        float p0[16], p1[16];
#pragma unroll
        for (int i = 0; i < 16; ++i) { p0[i] = fexp2(s0[i]); p1[i] = fexp2(s1[i]); }

#define R15_PV(PP, O, KS) do {                                                  \
        uint32_t w0 = pkbf(PP[(O) + 0], PP[(O) + 1]);                           \
        uint32_t w1 = pkbf(PP[(O) + 2], PP[(O) + 3]);                           \
        uint32_t w2 = pkbf(PP[(O) + 4], PP[(O) + 5]);                           \
        uint32_t w3 = pkbf(PP[(O) + 6], PP[(O) + 7]);                           \
        asm volatile("v_permlane32_swap_b32 %0, %1" : "+v"(w0), "+v"(w2));      \
        asm volatile("v_permlane32_swap_b32 %0, %1" : "+v"(w1), "+v"(w3));      \
        u32x4 pw = {w0, w1, w2, w3};                                            \
        bf16x8 pf = __builtin_bit_cast(bf16x8, pw);                             \
        const int cv = (((KS) * 2 + h) ^ swz8) * 8;                             \
        bf16x8 vf0 = *(const bf16x8*)&Vb[lq * 64 + cv];                         \
        bf16x8 vf1 = *(const bf16x8*)&Vb[(lq + 32) * 64 + cv];                  \
        accT0 = mfma32(vf0, pf, accT0);                                         \
        accT1 = mfma32(vf1, pf, accT1);                                         \
    } while (0)

        __builtin_amdgcn_s_setprio(1);
        R15_PV(p0, 0, 0);
        R15_PV(p0, 8, 1);
        R15_PV(p1, 0, 2);
        R15_PV(p1, 8, 3);
        __builtin_amdgcn_s_setprio(0);
#undef R15_PV

        float a16[16];
#pragma unroll
        for (int i = 0; i < 16; ++i) a16[i] = p0[i] + p1[i];
#pragma unroll
        for (int i = 0; i < 8; ++i) a16[i] += a16[i + 8];
#pragma unroll
        for (int i = 0; i < 4; ++i) a16[i] += a16[i + 4];
        float lt = (a16[0] + a16[1]) + (a16[2] + a16[3]);
        lt += __shfl_xor(lt, 32);
        l_run += lt;
    }

    // combine: waves 1-3 dump unnormalized partials into their OWN regions
    if (wave != 0) {
        float* pa = (float*)&arena[(size_t)wave * 8192];
#pragma unroll
        for (int r = 0; r < 16; ++r) {
            pa[r * 64 + lane]        = accT0[r];     // bank = lane%32: conflict-free
            pa[(16 + r) * 64 + lane] = accT1[r];
        }
        if (lane < 32) l_lds[wave][lane] = l_run;
    }
    __syncthreads();
    if (wave == 0) {
        float l_tot = l_run + l_lds[1][lq] + l_lds[2][lq] + l_lds[3][lq];
#pragma unroll
        for (int w = 1; w < 4; ++w) {
            const float* pa = (const float*)&arena[(size_t)w * 8192];
#pragma unroll
            for (int r = 0; r < 16; ++r) {
                accT0[r] += pa[r * 64 + lane];
                accT1[r] += pa[(16 + r) * 64 + lane];
            }
        }
        float inv = 1.f / l_tot;
        __bf16* Osw = &arena[0];                     // wave-0's region: free now
#pragma unroll
        for (int r = 0; r < 16; ++r) {
            int d0 = (r & 3) + 8 * (r >> 2) + 4 * h;
            Osw[lq * 72 + d0]      = (__bf16)(accT0[r] * inv);
            Osw[lq * 72 + 32 + d0] = (__bf16)(accT1[r] * inv);
        }
        asm volatile("s_waitcnt lgkmcnt(0)" ::: "memory");
        __builtin_amdgcn_sched_barrier(0);
        const int b = bh >> 4, head = bh & 15;
        const int qr = lane >> 1, seg = (lane & 1) * 32;
        __bf16* dst = &ctx[((size_t)b * SL + q0 + qr) * DM + head * HD + seg];
#pragma unroll
        for (int c = 0; c < 4; ++c)
            *(bf16x8*)&dst[c * 8] = *(const bf16x8*)&Osw[qr * 72 + seg + c * 8];
    }
}

extern "C" void kernel_launch(void* const* d_in, const int* in_sizes, int n_in,
                              void* d_out, int out_size, void* d_ws, size_t ws_size,
                              hipStream_t stream) {
    const float* x    = (const float*)d_in[0];
    const float* wqkv = (const float*)d_in[1];
    const float* wout = (const float*)d_in[2];
    float* out = (float*)d_out;                          // reference returns f32

    __bf16* ws    = (__bf16*)d_ws;
    __bf16* xb    = ws;                                  // 4M elems
    __bf16* wqkvT = xb    + (size_t)MROWS * DM;          // 3M
    __bf16* woutT = wqkvT + (size_t)3 * DM * DM;         // 1M
    __bf16* qbuf  = woutT + (size_t)DM * DM;             // 4M
    __bf16* kbuf  = qbuf  + (size_t)MROWS * DM;          // 4M
    __bf16* vtbuf = kbuf  + (size_t)MROWS * DM;          // 4M
    __bf16* ctxb  = vtbuf + (size_t)MROWS * DM;          // 4M (48MB total)

    r15_cast<<<dim3((MROWS * DM) / 1024), dim3(256), 0, stream>>>(x, xb, MROWS * DM);
    r15_transpose_cast<<<dim3(96, 32), dim3(256), 0, stream>>>(wqkv, wqkvT, DM, 3 * DM);
    r15_transpose_cast<<<dim3(32, 32), dim3(256), 0, stream>>>(wout, woutT, DM, DM);

    r15_gemm<1, 128><<<dim3(24, 32), dim3(256), 0, stream>>>(
        xb, wqkvT, (float*)nullptr, MROWS, 3 * DM, DM, qbuf, kbuf, vtbuf);

    r15_attn<<<dim3(2048), dim3(256), 0, stream>>>(qbuf, kbuf, vtbuf, ctxb);

    r15_gemm<0, 64><<<dim3(16, 32), dim3(256), 0, stream>>>(
        ctxb, woutT, out, MROWS, DM, DM,
        (__bf16*)nullptr, (__bf16*)nullptr, (__bf16*)nullptr);
}

// Round 16
// 136.209 us; speedup vs baseline: 2.5936x; 2.5936x over previous
//
#include <hip/hip_runtime.h>
#include <cstdint>
#include <cstddef>

typedef float f32x4 __attribute__((ext_vector_type(4)));
typedef float f32x16 __attribute__((ext_vector_type(16)));
typedef __bf16 bf16x8 __attribute__((ext_vector_type(8)));
typedef __bf16 bf16x4 __attribute__((ext_vector_type(4)));
typedef uint32_t u32x4 __attribute__((ext_vector_type(4)));

static constexpr int BSZ = 2, SL = 2048, DM = 1024, NH = 16, HD = 64;
static constexpr int MROWS = BSZ * SL;                 // 4096
static constexpr float LOG2E = 1.4426950408889634f;
static constexpr float QSCALE = 0.03125f * LOG2E;      // D^-0.5 * log2(e)

__device__ __forceinline__ f32x4 mfma16(bf16x8 a, bf16x8 b, f32x4 c) {
    return __builtin_amdgcn_mfma_f32_16x16x32_bf16(a, b, c, 0, 0, 0);
}
__device__ __forceinline__ f32x16 mfma32(bf16x8 a, bf16x8 b, f32x16 c) {
    return __builtin_amdgcn_mfma_f32_32x32x16_bf16(a, b, c, 0, 0, 0);
}
__device__ __forceinline__ uint32_t pkbf(float lo, float hi) {
    uint16_t a = __builtin_bit_cast(uint16_t, (__bf16)lo);
    uint16_t b = __builtin_bit_cast(uint16_t, (__bf16)hi);
    return ((uint32_t)b << 16) | (uint32_t)a;
}
// raw v_exp_f32 (2^x); inputs bounded, no denormal guard needed (r10-proven)
__device__ __forceinline__ float fexp2(float x) {
#if __has_builtin(__builtin_amdgcn_exp2f)
    return __builtin_amdgcn_exp2f(x);
#else
    float r; asm volatile("v_exp_f32 %0, %1" : "=v"(r) : "v"(x)); return r;
#endif
}
// async global->LDS, 16B per lane; lds dest = wave-uniform base + lane*16
__device__ __forceinline__ void gload16(const void* g, void* l) {
    __builtin_amdgcn_global_load_lds(
        (const __attribute__((address_space(1))) uint32_t*)g,
        (__attribute__((address_space(3))) uint32_t*)l, 16, 0, 0);
}

// ---------- cast f32 -> bf16, vectorized x4 ----------
__global__ __launch_bounds__(256) void r16_cast(const float* __restrict__ in,
                                                __bf16* __restrict__ out, int n) {
    int i = (blockIdx.x * 256 + threadIdx.x) * 4;
    if (i >= n) return;
    float4 v = *(const float4*)&in[i];
    bf16x4 o;
    o.x = (__bf16)v.x; o.y = (__bf16)v.y; o.z = (__bf16)v.z; o.w = (__bf16)v.w;
    *(bf16x4*)&out[i] = o;
}

// ---------- transpose [R][C] f32 -> [C][R] bf16 ----------
__global__ __launch_bounds__(256) void r16_transpose_cast(const float* __restrict__ in,
                                                          __bf16* __restrict__ out,
                                                          int R, int C) {
    __shared__ float tile[32][33];
    int c0 = blockIdx.x * 32, r0 = blockIdx.y * 32;
    int tx = threadIdx.x & 31, ty = threadIdx.x >> 5;   // 256 threads: ty 0..7
#pragma unroll
    for (int i = 0; i < 32; i += 8)
        tile[ty + i][tx] = in[(size_t)(r0 + ty + i) * C + c0 + tx];
    __syncthreads();
#pragma unroll
    for (int i = 0; i < 32; i += 8)
        out[(size_t)(c0 + ty + i) * R + r0 + tx] = (__bf16)tile[tx][ty + i];
}

// ---------- GEMM (r10-proven, BK=32, global_load_lds): C = A * Bt^T ----------
// EPI==1: scatter into Q (scaled), K, V^T.  EPI==0: f32 row-major out.
template <int EPI, int BN>
__global__ __launch_bounds__(256) void r16_gemm(
    const __bf16* __restrict__ A, const __bf16* __restrict__ Bt,
    float* __restrict__ ob, int M, int N, int K,
    __bf16* __restrict__ qb, __bf16* __restrict__ kb, __bf16* __restrict__ vtb)
{
    constexpr int BM = 128, BK = 32;
    constexpr int FN = BN / 32;               // acc cols per wave (128->4, 64->2)
    __shared__ __bf16 As[BM * BK];
    __shared__ __bf16 Bs[BN * BK];
    const int tid  = threadIdx.x;
    const int m0   = blockIdx.y * BM, n0 = blockIdx.x * BN;
    const int wave = tid >> 6, lane = tid & 63;
    const int lcol = lane & 15, lgrp = lane >> 4;
    const int wm   = (wave >> 1) * 64, wn = (wave & 1) * (BN / 2);
    const int grow = lane >> 2, gcol = (lane & 3) * 8;   // staging: 16 rows/chunk

    f32x4 acc[4][FN] = {};

    for (int k0 = 0; k0 < K; k0 += BK) {
        {
            const int cA0 = 2 * wave;
            gload16(&A[(size_t)(m0 + cA0 * 16 + grow) * K + k0 + gcol], &As[cA0 * 512]);
            gload16(&A[(size_t)(m0 + (cA0 + 1) * 16 + grow) * K + k0 + gcol], &As[(cA0 + 1) * 512]);
            if constexpr (BN == 128) {
                gload16(&Bt[(size_t)(n0 + cA0 * 16 + grow) * K + k0 + gcol], &Bs[cA0 * 512]);
                gload16(&Bt[(size_t)(n0 + (cA0 + 1) * 16 + grow) * K + k0 + gcol], &Bs[(cA0 + 1) * 512]);
            } else {
                gload16(&Bt[(size_t)(n0 + wave * 16 + grow) * K + k0 + gcol], &Bs[wave * 512]);
            }
        }
        __syncthreads();
        bf16x8 af[4], bfr[FN];
#pragma unroll
        for (int f = 0; f < 4; ++f)
            af[f] = *(const bf16x8*)&As[(wm + f * 16 + lcol) * BK + lgrp * 8];
#pragma unroll
        for (int f = 0; f < FN; ++f)
            bfr[f] = *(const bf16x8*)&Bs[(wn + f * 16 + lcol) * BK + lgrp * 8];
#pragma unroll
        for (int fm = 0; fm < 4; ++fm)
#pragma unroll
            for (int fn = 0; fn < FN; ++fn)
                acc[fm][fn] = mfma16(af[fm], bfr[fn], acc[fm][fn]);
        __syncthreads();
    }

#pragma unroll
    for (int fm = 0; fm < 4; ++fm) {
#pragma unroll
        for (int fn = 0; fn < FN; ++fn) {
            int n = n0 + wn + fn * 16 + lcol;
#pragma unroll
            for (int r = 0; r < 4; ++r) {
                int m = m0 + wm + fm * 16 + lgrp * 4 + r;
                float v = acc[fm][fn][r];
                if (EPI == 0) {
                    ob[(size_t)m * N + n] = v;               // f32 output
                } else {
                    int sec = n >> 10, nm = n & 1023;
                    int h = nm >> 6, d = nm & 63;
                    int b = m >> 11, s = m & 2047;
                    size_t bh = (size_t)(b * NH + h);
                    if (sec == 0)      qb[(bh * SL + s) * HD + d]  = (__bf16)(v * QSCALE);
                    else if (sec == 1) kb[(bh * SL + s) * HD + d]  = (__bf16)v;
                    else               vtb[(bh * HD + d) * SL + s] = (__bf16)v;
                }
            }
        }
    }
}

// ---------- flash attention: r12 structure, staging via global_load_lds ------
// grid (16, 32) XCD-swizzled; 4 waves x 32 q-rows, KVBLK=64, LDS dbuf.
// Swizzle preserved per rule #21: linear LDS dest + pre-swizzled global source
// column (scol = (lane&7)^(lane>>3)); read side identical to r12.
#define PV_STEP(a0,a1,a2,a3,a4,a5,a6,a7, KS) do {                               \
    uint32_t w0 = pkbf(a0, a1), w1 = pkbf(a2, a3);                              \
    uint32_t w2 = pkbf(a4, a5), w3 = pkbf(a6, a7);                              \
    asm volatile("v_permlane32_swap_b32 %0, %1" : "+v"(w0), "+v"(w2));          \
    asm volatile("v_permlane32_swap_b32 %0, %1" : "+v"(w1), "+v"(w3));          \
    u32x4 pw = {w0, w1, w2, w3};                                                \
    bf16x8 pf = __builtin_bit_cast(bf16x8, pw);                                 \
    const int cv = (((KS) * 2 + h) ^ swz8) * 8;                                 \
    bf16x8 vf0 = *(const bf16x8*)&Vl[lq * 64 + cv];                             \
    bf16x8 vf1 = *(const bf16x8*)&Vl[(lq + 32) * 64 + cv];                      \
    accT0 = mfma32(vf0, pf, accT0);                                             \
    accT1 = mfma32(vf1, pf, accT1);                                             \
} while (0)

// stage one 64x64 K tile + 64x64 V^T tile into buffer BUF via global_load_lds.
// wave w covers chunks 2w,2w+1 of each (chunk = 8 rows = 1KB).
#define STAGE(TI, BUF) do {                                                     \
    __bf16* Kb_ = &arena[(BUF) * 8192];                                         \
    __bf16* Vb_ = Kb_ + 4096;                                                   \
    const __bf16* Ks_ = Kg + (size_t)(TI) * 64 * HD;                            \
    const __bf16* Vs_ = Vg + (TI) * 64;                                         \
    gload16(Ks_ + (size_t)(wave * 16 + rsub) * HD + scol * 8,                   \
            Kb_ + wave * 1024);                                                 \
    gload16(Ks_ + (size_t)(wave * 16 + 8 + rsub) * HD + scol * 8,               \
            Kb_ + wave * 1024 + 512);                                           \
    gload16(Vs_ + (size_t)(wave * 16 + rsub) * SL + scol * 8,                   \
            Vb_ + wave * 1024);                                                 \
    gload16(Vs_ + (size_t)(wave * 16 + 8 + rsub) * SL + scol * 8,               \
            Vb_ + wave * 1024 + 512);                                           \
} while (0)

__global__ __launch_bounds__(256) void r16_attn(
    const __bf16* __restrict__ qb, const __bf16* __restrict__ kb,
    const __bf16* __restrict__ vtb, __bf16* __restrict__ ctx)
{
    __shared__ __bf16 arena[16384];      // 32KB: KV dbuf; epilogue Os aliases it
    // XCD-aware swizzle: 4 whole heads x 16 qblks per XCD (per-XCD K/V = 2MB < L2)
    const int L = blockIdx.x + 16 * blockIdx.y;
    const int xcd = L & 7, j = L >> 3;
    const int bh = xcd * 4 + (j & 3);
    const int qblk = j >> 2;
    const int tid  = threadIdx.x;
    const int wave = tid >> 6, lane = tid & 63;
    const int lq = lane & 31, h = lane >> 5;
    const int swz8 = lq & 7;
    const int q0 = qblk * 128 + wave * 32;

    const __bf16* Q  = qb  + ((size_t)bh * SL + q0) * HD;
    const __bf16* Kg = kb  + (size_t)bh * SL * HD;
    const __bf16* Vg = vtb + (size_t)bh * HD * SL;

    // staging lane geometry: row-in-chunk + PRE-SWIZZLED source column chunk
    const int rsub = lane >> 3;                  // 0..7
    const int scol = (lane & 7) ^ rsub;          // source col chunk (involution)

    bf16x8 qf[4];
#pragma unroll
    for (int t = 0; t < 4; ++t)
        qf[t] = *(const bf16x8*)&Q[(size_t)lq * HD + t * 16 + h * 8];

    f32x16 accT0 = {}, accT1 = {};
    float l_run = 0.f;

    constexpr int NT = SL / 64;          // 32 tiles
    STAGE(0, 0);
    asm volatile("s_waitcnt vmcnt(0)" ::: "memory");
    __builtin_amdgcn_s_barrier();
    __builtin_amdgcn_sched_barrier(0);

    for (int t = 0; t < NT; ++t) {
        const int cur = t & 1;
        if (t + 1 < NT) STAGE(t + 1, cur ^ 1);

        const __bf16* Kl = &arena[cur * 8192];
        const __bf16* Vl = Kl + 4096;

        f32x16 s0 = {}, s1 = {};
        __builtin_amdgcn_s_setprio(1);
#pragma unroll
        for (int t4 = 0; t4 < 4; ++t4) {
            const int cv = ((t4 * 2 + h) ^ swz8) * 8;
            bf16x8 kf0 = *(const bf16x8*)&Kl[lq * 64 + cv];
            bf16x8 kf1 = *(const bf16x8*)&Kl[(lq + 32) * 64 + cv];
            s0 = mfma32(kf0, qf[t4], s0);
            s1 = mfma32(kf1, qf[t4], s1);
        }
        __builtin_amdgcn_s_setprio(0);

        float p0[16], p1[16];
#pragma unroll
        for (int i = 0; i < 16; ++i) { p0[i] = fexp2(s0[i]); p1[i] = fexp2(s1[i]); }

        __builtin_amdgcn_s_setprio(1);
        PV_STEP(p0[0], p0[1], p0[2], p0[3], p0[4], p0[5], p0[6], p0[7], 0);
        PV_STEP(p0[8], p0[9], p0[10], p0[11], p0[12], p0[13], p0[14], p0[15], 1);
        PV_STEP(p1[0], p1[1], p1[2], p1[3], p1[4], p1[5], p1[6], p1[7], 2);
        PV_STEP(p1[8], p1[9], p1[10], p1[11], p1[12], p1[13], p1[14], p1[15], 3);
        __builtin_amdgcn_s_setprio(0);

        float a16[16];
#pragma unroll
        for (int i = 0; i < 16; ++i) a16[i] = p0[i] + p1[i];
#pragma unroll
        for (int i = 0; i < 8; ++i) a16[i] += a16[i + 8];
#pragma unroll
        for (int i = 0; i < 4; ++i) a16[i] += a16[i + 4];
        float lt = (a16[0] + a16[1]) + (a16[2] + a16[3]);
        lt += __shfl_xor(lt, 32);
        l_run += lt;

        // next tile ready: drain this iteration's staging loads, then barrier.
        asm volatile("s_waitcnt vmcnt(0)" ::: "memory");
        __builtin_amdgcn_s_barrier();
        __builtin_amdgcn_sched_barrier(0);
    }

    // epilogue: all waves done with KV arena -> alias Os transpose buffer
    float inv = 1.f / l_run;
    __syncthreads();                      // full drain fine here (once)
    __bf16* Osw = &arena[wave * 2304];   // 32 rows x 72
#pragma unroll
    for (int r = 0; r < 16; ++r) {
        int d0 = (r & 3) + 8 * (r >> 2) + 4 * h;
        Osw[lq * 72 + d0]      = (__bf16)(accT0[r] * inv);
        Osw[lq * 72 + 32 + d0] = (__bf16)(accT1[r] * inv);
    }
    asm volatile("s_waitcnt lgkmcnt(0)" ::: "memory");
    __builtin_amdgcn_sched_barrier(0);
    const int b = bh >> 4, head = bh & 15;
    const int qr = lane >> 1, seg = (lane & 1) * 32;
    __bf16* dst = &ctx[((size_t)b * SL + q0 + qr) * DM + head * HD + seg];
#pragma unroll
    for (int c = 0; c < 4; ++c)
        *(bf16x8*)&dst[c * 8] = *(const bf16x8*)&Osw[qr * 72 + seg + c * 8];
}

extern "C" void kernel_launch(void* const* d_in, const int* in_sizes, int n_in,
                              void* d_out, int out_size, void* d_ws, size_t ws_size,
                              hipStream_t stream) {
    const float* x    = (const float*)d_in[0];
    const float* wqkv = (const float*)d_in[1];
    const float* wout = (const float*)d_in[2];
    float* out = (float*)d_out;                          // reference returns f32

    __bf16* ws    = (__bf16*)d_ws;
    __bf16* xb    = ws;                                  // 4M elems
    __bf16* wqkvT = xb    + (size_t)MROWS * DM;          // 3M
    __bf16* woutT = wqkvT + (size_t)3 * DM * DM;         // 1M
    __bf16* qbuf  = woutT + (size_t)DM * DM;             // 4M
    __bf16* kbuf  = qbuf  + (size_t)MROWS * DM;          // 4M
    __bf16* vtbuf = kbuf  + (size_t)MROWS * DM;          // 4M
    __bf16* ctxb  = vtbuf + (size_t)MROWS * DM;          // 4M (48MB total)

    r16_cast<<<dim3((MROWS * DM) / 1024), dim3(256), 0, stream>>>(x, xb, MROWS * DM);
    r16_transpose_cast<<<dim3(96, 32), dim3(256), 0, stream>>>(wqkv, wqkvT, DM, 3 * DM);
    r16_transpose_cast<<<dim3(32, 32), dim3(256), 0, stream>>>(wout, woutT, DM, DM);

    r16_gemm<1, 128><<<dim3(24, 32), dim3(256), 0, stream>>>(
        xb, wqkvT, (float*)nullptr, MROWS, 3 * DM, DM, qbuf, kbuf, vtbuf);

    r16_attn<<<dim3(16, 32), dim3(256), 0, stream>>>(qbuf, kbuf, vtbuf, ctxb);

    r16_gemm<0, 64><<<dim3(16, 32), dim3(256), 0, stream>>>(
        ctxb, woutT, out, MROWS, DM, DM,
        (__bf16*)nullptr, (__bf16*)nullptr, (__bf16*)nullptr);
}